// Round 1
// 389.799 us; speedup vs baseline: 1.0360x; 1.0360x over previous
//
#include <hip/hip_runtime.h>

#define EMB 128
#define NN 50000
#define BB 1024
#define LL 50
#define NBK 49     // ceil(NN/1024) buckets
#define NEB 512    // emit/count chunks

typedef float f32x4 __attribute__((ext_vector_type(4)));
typedef float f32x2 __attribute__((ext_vector_type(2)));
typedef unsigned short u16;
typedef unsigned int u32;
typedef unsigned long long u64;
typedef u16 u16x4 __attribute__((ext_vector_type(4)));
typedef u32 u32x4 __attribute__((ext_vector_type(4)));
typedef short bf16x8 __attribute__((ext_vector_type(8)));   // 8 bf16 in 4 VGPRs

__device__ __forceinline__ float u2f(u16 u) {
    union { unsigned int i; float f; } v; v.i = ((unsigned int)u) << 16; return v.f;
}
__device__ __forceinline__ u16 f2b(float f) {
    union { float f; unsigned int i; } v; v.f = f;
    unsigned int i = v.i;
    return (u16)((i + 0x7FFFu + ((i >> 16) & 1u)) >> 16);   // RNE
}
__device__ __forceinline__ float lo2f(u32 w) { return u2f((u16)(w & 0xffffu)); }
__device__ __forceinline__ float hi2f(u32 w) { return u2f((u16)(w >> 16)); }
__device__ __forceinline__ float sigmoidf_(float x) { return 1.f / (1.f + __expf(-x)); }

__device__ __forceinline__ bf16x8 ld_cvt8(const float* p) {
    f32x4 v0 = *(const f32x4*)p;
    f32x4 v1 = *(const f32x4*)(p + 4);
    union { u16 u[8]; bf16x8 b; } r;
#pragma unroll
    for (int t = 0; t < 4; t++) { r.u[t] = f2b(v0[t]); r.u[4 + t] = f2b(v1[t]); }
    return r.b;
}

// ================= prep: converts + per-(chunk,bucket) counts (LDS only) =================
__global__ __launch_bounds__(256) void prep_kernel(
    const float* __restrict__ emb, const float* __restrict__ A, const float* __restrict__ D,
    const float* __restrict__ wih, const float* __restrict__ whh,
    const float* __restrict__ Win, const float* __restrict__ Wout,
    u16* __restrict__ emb_bf, u16* __restrict__ A_bf, u16* __restrict__ D_bf,
    u16* __restrict__ wih_bf, u16* __restrict__ whh_bf,
    u16* __restrict__ Win_bf, u16* __restrict__ Wout_bf,
    const int* __restrict__ rowi, int* __restrict__ bcnt,
    int E, int chunk)
{
    __shared__ int lc[NBK];
    int gid = blockIdx.x * 256 + threadIdx.x;
    int stride = gridDim.x * 256;
    int tid = threadIdx.x;
    if (blockIdx.x < NEB) {
        if (tid < NBK) lc[tid] = 0;
        __syncthreads();
        int beg = blockIdx.x * chunk, end = min(E, beg + chunk);
        for (int e = beg + tid; e < end; e += 256)
            atomicAdd(&lc[rowi[e] >> 10], 1);
        __syncthreads();
        if (tid < NBK) bcnt[blockIdx.x * NBK + tid] = lc[tid];
    }
    for (int i = gid; i < 1600000; i += stride) {
        f32x4 v = *(const f32x4*)(emb + (size_t)i * 4);
        u16x4 p;
#pragma unroll
        for (int t = 0; t < 4; t++) p[t] = f2b(v[t]);
        *(u16x4*)(emb_bf + (size_t)i * 4) = p;
    }
    for (int i = gid; i < 2277376; i += stride) {
        const float* s; u16* d; int off;
        if (i < 1048576)      { s = A;    d = A_bf;    off = i; }
        else if (i < 2097152) { s = D;    d = D_bf;    off = i - 1048576; }
        else if (i < 2195456) { s = wih;  d = wih_bf;  off = i - 2097152; }
        else if (i < 2244608) { s = whh;  d = whh_bf;  off = i - 2195456; }
        else if (i < 2260992) { s = Win;  d = Win_bf;  off = i - 2244608; }
        else                  { s = Wout; d = Wout_bf; off = i - 2260992; }
        d[off] = f2b(s[off]);
    }
}

// per-bucket exclusive scan over chunks -> LOCAL bases + bucket totals
__global__ __launch_bounds__(512) void bktscan_kernel(
    const int* __restrict__ bcnt, int* __restrict__ sofs, int* __restrict__ btot)
{
    __shared__ int ps[512];
    int k = blockIdx.x, t = threadIdx.x;
    int c = bcnt[t * NBK + k];
    ps[t] = c; __syncthreads();
    for (int off = 1; off < 512; off <<= 1) {
        int v = (t >= off) ? ps[t - off] : 0;
        __syncthreads();
        ps[t] += v; __syncthreads();
    }
    sofs[t * NBK + k] = ps[t] - c;
    if (t == 511) btot[k] = ps[511];
}

__global__ __launch_bounds__(64) void btotal_kernel(
    const int* __restrict__ btot, int* __restrict__ bofs, int E)
{
    if (threadIdx.x == 0) {
        int run = 0;
        for (int k = 0; k < NBK; k++) { bofs[k] = run; run += btot[k]; }
        bofs[NBK] = E;
    }
}

__global__ __launch_bounds__(256) void emit_kernel(
    const int* __restrict__ rowi, const int* __restrict__ coli, const float* __restrict__ val,
    const int* __restrict__ sofs, const int* __restrict__ bofs,
    u64* __restrict__ egs, int E, int chunk)
{
    __shared__ int cur[NBK];
    int b = blockIdx.x, tid = threadIdx.x;
    if (tid < NBK) cur[tid] = bofs[tid] + sofs[b * NBK + tid];
    __syncthreads();
    int beg = b * chunk, end = min(E, beg + chunk);
    for (int e = beg + tid; e < end; e += 256) {
        int r = rowi[e];
        int slot = atomicAdd(&cur[r >> 10], 1);
        u64 entry = ((u64)(u32)(r & 1023) << 32)
                  | (u64)((u32)(u16)coli[e] | ((u32)f2b(val[e]) << 16));
        egs[slot] = entry;
    }
}

__global__ __launch_bounds__(1024) void binsort2_kernel(
    const u64* __restrict__ egs, const int* __restrict__ bofs,
    int* __restrict__ row_ptr, u32* __restrict__ eg, int E)
{
    __shared__ int cnt_s[1024];
    __shared__ int ps[1024];
    int k = blockIdx.x, tid = threadIdx.x;
    int r0 = k << 10;
    int beg = bofs[k], end = bofs[k + 1];
    cnt_s[tid] = 0;
    __syncthreads();
    for (int i = beg + tid; i < end; i += 1024)
        atomicAdd(&cnt_s[(int)(egs[i] >> 32)], 1);
    __syncthreads();
    int v = cnt_s[tid];
    ps[tid] = v; __syncthreads();
    for (int off = 1; off < 1024; off <<= 1) {
        int t = (tid >= off) ? ps[tid - off] : 0;
        __syncthreads();
        ps[tid] += t; __syncthreads();
    }
    int ex = beg + ps[tid] - v;
    if (r0 + tid <= NN) row_ptr[r0 + tid] = ex;
    if (k == NBK - 1 && tid == 1023) row_ptr[NN] = E;
    cnt_s[tid] = ex;
    __syncthreads();
    for (int i = beg + tid; i < end; i += 1024) {
        u64 entry = egs[i];
        int rlo = (int)(entry >> 32);
        int p = atomicAdd(&cnt_s[rlo], 1);
        eg[p] = (u32)entry;
    }
}

// One wave per row. 64 lanes = 4 edge-groups x 16 feature-blocks.
// Each lane loads dwordx4 (8 bf16 feats) per edge -> 4 edges per wave-instruction.
// 3-stage software pipeline: eg loads 2 pairs ahead, data loads 1 pair ahead.
// Tails handled by clamp + zero-val mask; cross-group reduce via shfl_xor(16/32).
template<int FUSE>
__global__ __launch_bounds__(256) void gatherb_kernel(
    const int* __restrict__ row_ptr, const u32* __restrict__ eg,
    const u16* __restrict__ src, const float* __restrict__ emb0,
    u16* __restrict__ dst_bf, float* __restrict__ dst_f)
{
    int wave = threadIdx.x >> 6;
    int lane = threadIdx.x & 63;
    int g  = lane >> 4;          // edge slot within chunk-of-4
    int fl = lane & 15;          // feature block: features fl*8 .. fl*8+7
    int r = blockIdx.x * 4 + wave;
    if (r >= NN) return;
    int beg = row_ptr[r], end = row_ptr[r + 1];

    float acc[8];
#pragma unroll
    for (int t = 0; t < 8; t++) acc[t] = 0.f;

    if (beg < end) {
        int last = end - 1;
        int npair = (end - beg + 7) >> 3;       // pairs of 4-edge chunks (8 edges)
        // S(0): eg for pair 0
        u32 pkA = eg[min(beg + g, last)];
        u32 pkB = eg[min(beg + 4 + g, last)];
        // X(0): data for pair 0
        float vA = (beg + g     < end) ? u2f((u16)(pkA >> 16)) : 0.f;
        float vB = (beg + 4 + g < end) ? u2f((u16)(pkB >> 16)) : 0.f;
        u32x4 xA = *(const u32x4*)(src + ((pkA & 0xffffu) << 7) + (fl << 3));
        u32x4 xB = *(const u32x4*)(src + ((pkB & 0xffffu) << 7) + (fl << 3));
        // S(1): eg for pair 1
        pkA = eg[min(beg + 8  + g, last)];
        pkB = eg[min(beg + 12 + g, last)];

        int e = beg;
        for (int p = 0; p < npair; p++) {
            // grab consume-ready pair p
            float cvA = vA, cvB = vB;
            u32x4 cxA = xA, cxB = xB;
            // X(p+1): issue data loads for next pair (safe clamped if past end)
            int eN = e + 8;
            vA = (eN + g     < end) ? u2f((u16)(pkA >> 16)) : 0.f;
            vB = (eN + 4 + g < end) ? u2f((u16)(pkB >> 16)) : 0.f;
            xA = *(const u32x4*)(src + ((pkA & 0xffffu) << 7) + (fl << 3));
            xB = *(const u32x4*)(src + ((pkB & 0xffffu) << 7) + (fl << 3));
            // S(p+2): issue eg loads two pairs ahead
            int eS = e + 16;
            pkA = eg[min(eS + g, last)];
            pkB = eg[min(eS + 4 + g, last)];
            // C(p): consume pair p
#pragma unroll
            for (int t = 0; t < 4; t++) {
                acc[2 * t]     += cvA * lo2f(cxA[t]);
                acc[2 * t + 1] += cvA * hi2f(cxA[t]);
            }
#pragma unroll
            for (int t = 0; t < 4; t++) {
                acc[2 * t]     += cvB * lo2f(cxB[t]);
                acc[2 * t + 1] += cvB * hi2f(cxB[t]);
            }
            e += 8;
        }
    }

    // reduce partial sums across the 4 edge-groups (lane bits 4 and 5)
#pragma unroll
    for (int t = 0; t < 8; t++) {
        acc[t] += __shfl_xor(acc[t], 16);
        acc[t] += __shfl_xor(acc[t], 32);
    }

    if (lane < 16) {
        if (FUSE) {
            u32x4 s = *(const u32x4*)(src + ((u32)r << 7) + (lane << 3));
            const float* e0p = emb0 + ((size_t)r << 7) + (lane << 3);
            f32x4 e0a = *(const f32x4*)e0p;
            f32x4 e0b = *(const f32x4*)(e0p + 4);
            f32x4 o0, o1;
#pragma unroll
            for (int t = 0; t < 2; t++) {
                o0[2 * t]     = acc[2 * t]     + e0a[2 * t]     + lo2f(s[t]);
                o0[2 * t + 1] = acc[2 * t + 1] + e0a[2 * t + 1] + hi2f(s[t]);
                o1[2 * t]     = acc[4 + 2 * t]     + e0b[2 * t]     + lo2f(s[2 + t]);
                o1[2 * t + 1] = acc[4 + 2 * t + 1] + e0b[2 * t + 1] + hi2f(s[2 + t]);
            }
            float* dp = dst_f + ((size_t)r << 7) + (lane << 3);
            *(f32x4*)dp = o0;
            *(f32x4*)(dp + 4) = o1;
        } else {
            u32x4 w;
#pragma unroll
            for (int t = 0; t < 4; t++)
                w[t] = (u32)f2b(acc[2 * t]) | ((u32)f2b(acc[2 * t + 1]) << 16);
            *(u32x4*)(dst_bf + ((size_t)r << 7) + (lane << 3)) = w;
        }
    }
}

// ================= Part 2: LineConv (bf16 MFMA chain) =================
__global__ __launch_bounds__(128) void sess_pool_kernel(
    const int* __restrict__ items, const float* __restrict__ emb,
    const float* __restrict__ slen, float* __restrict__ sess, u16* __restrict__ sessT)
{
    int b = blockIdx.x, d = threadIdx.x;
    const int* it = items + b * LL;
    float acc = 0.f;
    for (int l = 0; l < LL; l++) {
        int idx = it[l];
        if (idx > 0) acc += emb[(size_t)(idx - 1) * EMB + d];
    }
    float v = acc / slen[b];
    sess[b * EMB + d] = v;
    sessT[d * BB + b] = f2b(v);
}

// C[1024,128] = M_bf @ Xt_bf^T. 64 blocks x 4 waves; wave owns (16-row tile, 2 col-tiles).
template<int WT, int WF>
__global__ __launch_bounds__(256) void mm_mfma_kernel(
    const u16* __restrict__ M_bf, const u16* __restrict__ Xt_bf,
    u16* __restrict__ Ct_bf, float* __restrict__ C_f)
{
    int tid = threadIdx.x;
    int wv = tid >> 6, lane = tid & 63, cl = lane & 15, kg = lane >> 4;
    int rbase = blockIdx.x * 16;
    f32x4 acc[2];
    acc[0] = (f32x4)0.f; acc[1] = (f32x4)0.f;
    const u16* arow = M_bf + (size_t)(rbase + cl) * BB + kg * 8;
    const u16* brow = Xt_bf + (size_t)(wv * 32 + cl) * BB + kg * 8;   // col-tiles 2wv, 2wv+1
#pragma unroll 4
    for (int k0 = 0; k0 < BB; k0 += 32) {
        bf16x8 a  = *(const bf16x8*)(arow + k0);
        bf16x8 b0 = *(const bf16x8*)(brow + k0);
        bf16x8 b1 = *(const bf16x8*)(brow + (size_t)16 * BB + k0);
        acc[0] = __builtin_amdgcn_mfma_f32_16x16x32_bf16(a, b0, acc[0], 0, 0, 0);
        acc[1] = __builtin_amdgcn_mfma_f32_16x16x32_bf16(a, b1, acc[1], 0, 0, 0);
    }
#pragma unroll
    for (int nt = 0; nt < 2; nt++) {
        int col = (wv * 2 + nt) * 16 + cl;
#pragma unroll
        for (int j = 0; j < 4; j++) {
            int row = rbase + kg * 4 + j;
            if (WF) C_f[(size_t)row * EMB + col] = acc[nt][j];
            if (WT) Ct_bf[(size_t)col * BB + row] = f2b(acc[nt][j]);
        }
    }
}

__global__ __launch_bounds__(256) void out1_kernel(
    const float* __restrict__ a, const float* __restrict__ b,
    const float* __restrict__ c, float* __restrict__ o, int n)
{
    int i = blockIdx.x * 256 + threadIdx.x;
    if (i < n) o[i] = a[i] + b[i] + c[i];
}

// ================= Part 3: GNN (bf16 MFMA) =================
__global__ __launch_bounds__(256) void gemm1_kernel(
    const float* __restrict__ hidden,
    const u16* __restrict__ W_in_bf, const u16* __restrict__ W_out_bf,
    const float* __restrict__ b_in, const float* __restrict__ b_out,
    u16* __restrict__ hT, int b0)
{
    int blk = blockIdx.x;
    int b = b0 + blk;
    int tid = threadIdx.x;
    int wv = tid >> 6, lane = tid & 63, cl = lane & 15, kg = lane >> 4;
    const float* hsrc = hidden + (size_t)b * LL * EMB;
    int mr = wv * 16 + cl;
    f32x4 acc[16];
#pragma unroll
    for (int nt = 0; nt < 16; nt++) acc[nt] = (f32x4)0.f;
#pragma unroll
    for (int ks = 0; ks < 4; ks++) {
        int k0 = ks * 32;
        bf16x8 a = (mr < LL) ? ld_cvt8(hsrc + mr * 128 + k0 + kg * 8) : (bf16x8)0;
#pragma unroll
        for (int nt = 0; nt < 16; nt++) {
            const u16* wsrc = (nt < 8) ? W_in_bf : W_out_bf;
            int wr = (nt & 7) * 16 + cl;
            bf16x8 bf = *(const bf16x8*)(wsrc + (size_t)wr * 128 + k0 + kg * 8);
            acc[nt] = __builtin_amdgcn_mfma_f32_16x16x32_bf16(a, bf, acc[nt], 0, 0, 0);
        }
    }
#pragma unroll
    for (int nt = 0; nt < 16; nt++) {
        int col = nt * 16 + cl;
        float bias = (col < 128) ? b_in[col] : b_out[col - 128];
        int r0 = wv * 16 + kg * 4;
        u16x4 p;
#pragma unroll
        for (int j = 0; j < 4; j++)
            p[j] = (r0 + j < LL) ? f2b(acc[nt][j] + bias) : (u16)0;
        *(u16x4*)&hT[((size_t)blk * 256 + col) * 64 + r0] = p;
    }
}

// Fused einsum + GRU gates per session: inputs never touch HBM.
__global__ __launch_bounds__(256) void gnn_tail_kernel(
    const u16* __restrict__ hT,
    const float* __restrict__ A_gnn, const int* __restrict__ alias_pos,
    const float* __restrict__ b_iah, const float* __restrict__ b_oah,
    const float* __restrict__ hidden,
    const u16* __restrict__ w_ih_bf, const float* __restrict__ b_ih,
    const u16* __restrict__ w_hh_bf, const float* __restrict__ b_hh,
    float* __restrict__ hy, int b0)
{
    __shared__ __attribute__((aligned(16))) u16 AioHs[64 * 128];   // 16 KB
    __shared__ __attribute__((aligned(16))) u16 hTsXs[256 * 72];   // 36.9 KB
    int blk = blockIdx.x;
    int b = b0 + blk;
    int tid = threadIdx.x;
    int wv = tid >> 6, lane = tid & 63, cl = lane & 15, kg = lane >> 4;

    for (int i = tid; i < 64 * 32; i += 256) {
        int row = i >> 5, c4 = i & 31;
        u16x4 p = (u16x4)0;
        if (row < LL) {
            int pos = alias_pos[b * LL + row];
            const float* ar = A_gnn + ((size_t)b * LL + pos) * (2 * LL);
#pragma unroll
            for (int t = 0; t < 4; t++) {
                int jp = c4 * 4 + t;
                int col = (jp < 64) ? jp : (50 + (jp - 64));
                int ok = (jp < 64) ? (jp < LL) : ((jp - 64) < LL);
                if (ok) p[t] = f2b(ar[col]);
            }
        }
        *(u16x4*)((char*)AioHs + row * 256 + ((c4 * 8) ^ ((row & 7) << 4))) = p;
    }
    for (int i = tid; i < 2048; i += 256) {
        int col = i >> 3, k8 = (i & 7) * 8;
        const u16* src = hT + ((size_t)blk * 256 + col) * 64 + k8;
        *(u16x4*)&hTsXs[col * 72 + k8]     = *(const u16x4*)src;
        *(u16x4*)&hTsXs[col * 72 + k8 + 4] = *(const u16x4*)(src + 4);
    }
    __syncthreads();

    f32x4 acc[16];
#pragma unroll
    for (int nt = 0; nt < 16; nt++) acc[nt] = (f32x4)0.f;
#pragma unroll
    for (int ks = 0; ks < 2; ks++) {
#pragma unroll
        for (int nt = 0; nt < 16; nt++) {
            int koff = (nt < 8) ? 0 : 64;
            int k0 = koff + ks * 32;
            int mr = wv * 16 + cl;
            bf16x8 a = *(const bf16x8*)((const char*)AioHs + mr * 256 +
                        (((k0 << 1) + (kg << 4)) ^ ((mr & 7) << 4)));
            bf16x8 bf = *(const bf16x8*)&hTsXs[(nt * 16 + cl) * 72 + ks * 32 + kg * 8];
            acc[nt] = __builtin_amdgcn_mfma_f32_16x16x32_bf16(a, bf, acc[nt], 0, 0, 0);
        }
    }
    __syncthreads();

#pragma unroll
    for (int nt = 0; nt < 16; nt++) {
        int dp = nt * 16 + cl;
        float bias = (dp < 128) ? b_iah[dp] : b_oah[dp - 128];
#pragma unroll
        for (int j = 0; j < 4; j++) {
            int i = wv * 16 + kg * 4 + j;
            *(u16*)((char*)hTsXs + i * 512 + ((dp * 2) ^ ((i & 7) << 4))) =
                f2b(acc[nt][j] + bias);
        }
    }
    const float* hsrc = hidden + (size_t)b * LL * EMB;
#pragma unroll
    for (int i2 = 0; i2 < 8; i2++) {
        int lin = i2 * 256 + tid;
        int row = lin >> 5, c4 = lin & 31;
        u16x4 p = (u16x4)0;
        if (row < LL) {
            f32x4 v = *(const f32x4*)(hsrc + row * 128 + c4 * 4);
#pragma unroll
            for (int t = 0; t < 4; t++) p[t] = f2b(v[t]);
        }
        *(u16x4*)((char*)AioHs + row * 256 + ((c4 * 8) ^ ((row & 7) << 4))) = p;
    }
    __syncthreads();

    f32x4 acc_ri[4][2][2];
    f32x4 acc_n1[4][2];
    f32x4 acc_n2[4][2];
#pragma unroll
    for (int mt = 0; mt < 4; mt++)
#pragma unroll
        for (int t = 0; t < 2; t++) {
            acc_ri[mt][0][t] = (f32x4)0.f; acc_ri[mt][1][t] = (f32x4)0.f;
            acc_n1[mt][t] = (f32x4)0.f; acc_n2[mt][t] = (f32x4)0.f;
        }

#pragma unroll
    for (int ks = 0; ks < 8; ks++) {
        int k0 = ks * 32;
        bf16x8 a[4];
#pragma unroll
        for (int mt = 0; mt < 4; mt++) {
            int mr = mt * 16 + cl;
            a[mt] = *(const bf16x8*)((const char*)hTsXs + mr * 512 +
                     (((k0 << 1) + (kg << 4)) ^ ((mr & 7) << 4)));
        }
#pragma unroll
        for (int g = 0; g < 3; g++)
#pragma unroll
            for (int t = 0; t < 2; t++) {
                int brow = g * 128 + wv * 32 + t * 16 + cl;
                bf16x8 bw = *(const bf16x8*)(w_ih_bf + (size_t)brow * 256 + k0 + kg * 8);
#pragma unroll
                for (int mt = 0; mt < 4; mt++) {
                    f32x4* dst = (g < 2) ? &acc_ri[mt][g][t] : &acc_n1[mt][t];
                    *dst = __builtin_amdgcn_mfma_f32_16x16x32_bf16(a[mt], bw, *dst, 0, 0, 0);
                }
            }
    }
#pragma unroll
    for (int ks = 0; ks < 4; ks++) {
        int k0 = ks * 32;
        bf16x8 a[4];
#pragma unroll
        for (int mt = 0; mt < 4; mt++) {
            int mr = mt * 16 + cl;
            a[mt] = *(const bf16x8*)((const char*)AioHs + mr * 256 +
                     (((k0 << 1) + (kg << 4)) ^ ((mr & 7) << 4)));
        }
#pragma unroll
        for (int g = 0; g < 3; g++)
#pragma unroll
            for (int t = 0; t < 2; t++) {
                int brow = g * 128 + wv * 32 + t * 16 + cl;
                bf16x8 bw = *(const bf16x8*)(w_hh_bf + (size_t)brow * 128 + k0 + kg * 8);
#pragma unroll
                for (int mt = 0; mt < 4; mt++) {
                    f32x4* dst = (g < 2) ? &acc_ri[mt][g][t] : &acc_n2[mt][t];
                    *dst = __builtin_amdgcn_mfma_f32_16x16x32_bf16(a[mt], bw, *dst, 0, 0, 0);
                }
            }
    }

#pragma unroll
    for (int t = 0; t < 2; t++) {
        int d = wv * 32 + t * 16 + cl;
        float br = b_ih[d] + b_hh[d];
        float bi = b_ih[128 + d] + b_hh[128 + d];
        float bn1 = b_ih[256 + d], bn2 = b_hh[256 + d];
#pragma unroll
        for (int mt = 0; mt < 4; mt++)
#pragma unroll
            for (int j = 0; j < 4; j++) {
                int row = mt * 16 + kg * 4 + j;
                if (row >= LL) continue;
                float rg = sigmoidf_(acc_ri[mt][0][t][j] + br);
                float ig = sigmoidf_(acc_ri[mt][1][t][j] + bi);
                float ng = tanhf(acc_n1[mt][t][j] + bn1 + rg * (acc_n2[mt][t][j] + bn2));
                u16 hb = *(const u16*)((const char*)AioHs + row * 256 + ((d * 2) ^ ((row & 7) << 4)));
                float h = u2f(hb);
                hy[((size_t)b * LL + row) * 128 + d] = ng + ig * (h - ng);
            }
    }
}

extern "C" void kernel_launch(void* const* d_in, const int* in_sizes, int n_in,
                              void* d_out, int out_size, void* d_ws, size_t ws_size,
                              hipStream_t stream) {
    (void)n_in; (void)out_size; (void)ws_size;
    const int*   adj_row      = (const int*)d_in[0];
    const int*   adj_col      = (const int*)d_in[1];
    const float* adj_val      = (const float*)d_in[2];
    const float* embedding    = (const float*)d_in[3];
    const int*   session_item = (const int*)d_in[4];
    const float* session_len  = (const float*)d_in[5];
    const float* Dm           = (const float*)d_in[6];
    const float* A_sess       = (const float*)d_in[7];
    const float* A_gnn        = (const float*)d_in[8];
    const int*   alias_pos    = (const int*)d_in[9];
    const float* hidden       = (const float*)d_in[10];
    const float* W_in         = (const float*)d_in[11];
    const float* b_in         = (const float*)d_in[12];
    const float* W_out        = (const float*)d_in[13];
    const float* b_out        = (const float*)d_in[14];
    const float* w_ih         = (const float*)d_in[15];
    const float* b_ih         = (const float*)d_in[16];
    const float* w_hh         = (const float*)d_in[17];
    const float* b_hh         = (const float*)d_in[18];
    const float* b_iah        = (const float*)d_in[19];
    const float* b_oah        = (const float*)d_in[20];
    const int E = in_sizes[0];

    float* out0 = (float*)d_out;
    float* out1 = out0 + 6400000;
    float* out2 = out1 + 131072;

    float* ws = (float*)d_ws;
    u16*  emb_bf  = (u16*)ws;                    // [0, 3.2M) live through gathers
    int*  bcnt  = (int*)(ws + 3200000);          // scratch under accA region
    int*  sofs  = (int*)(ws + 3230000);
    int*  btot  = (int*)(ws + 3260000);
    u16*  accA_bf = (u16*)(ws + 3200000);        // [3.2M, 6.4M) gather<0> out
    u32*  eg    = (u32*)(ws + 6400000);          // [6.4M, 8.0M)
    u64*  egs   = (u64*)(ws + 8000000);          // [8.0M, 11.2M)
    float* sess  = ws + 11200000;
    u16*   sessT = (u16*)(ws + 11350000);
    u16*   t1T   = (u16*)(ws + 11400000);
    u16*   s1T   = (u16*)(ws + 11450000);
    u16*   t2T   = (u16*)(ws + 11500000);
    float* s1    = ws + 11550000;
    float* s2    = ws + 11700000;
    u16*   A_bf  = (u16*)(ws + 11850000);
    u16*   D_bf  = (u16*)(ws + 12400000);
    int*   row_ptr = (int*)(ws + 12950000);
    int*   bofs    = row_ptr + NN + 1;
    u16* hT        = (u16*)ws;                   // part-3 overlay (emb/accA dead)
    u16* w_ih_bf   = (u16*)(ws + 13107200);
    u16* w_hh_bf   = w_ih_bf + 98304;
    u16* W_in_bf   = w_hh_bf + 49152;
    u16* W_out_bf  = W_in_bf + 16384;

    int chunk = (E + NEB - 1) / NEB;

    // ---- prep: converts + chunked bucket counts (no global atomics) ----
    prep_kernel<<<2048, 256, 0, stream>>>(embedding, A_sess, Dm, w_ih, w_hh, W_in, W_out,
                                          emb_bf, A_bf, D_bf, w_ih_bf, w_hh_bf, W_in_bf, W_out_bf,
                                          adj_row, bcnt, E, chunk);

    // ---- Part 1: bucket sort + 2 bf16 gather layers ----
    bktscan_kernel<<<NBK, 512, 0, stream>>>(bcnt, sofs, btot);
    btotal_kernel<<<1, 64, 0, stream>>>(btot, bofs, E);
    emit_kernel<<<NEB, 256, 0, stream>>>(adj_row, adj_col, adj_val, sofs, bofs, egs, E, chunk);
    binsort2_kernel<<<NBK, 1024, 0, stream>>>(egs, bofs, row_ptr, eg, E);
    gatherb_kernel<0><<<(NN + 3) / 4, 256, 0, stream>>>(row_ptr, eg, emb_bf, embedding, accA_bf, (float*)nullptr);
    gatherb_kernel<1><<<(NN + 3) / 4, 256, 0, stream>>>(row_ptr, eg, accA_bf, embedding, (u16*)nullptr, out0);

    // ---- Part 2: LineConv (MFMA chain, re-associated s_next = D @ (A @ s)) ----
    sess_pool_kernel<<<BB, 128, 0, stream>>>(session_item, embedding, session_len, sess, sessT);
    mm_mfma_kernel<1, 0><<<64, 256, 0, stream>>>(A_bf, sessT, t1T, (float*)nullptr);
    mm_mfma_kernel<1, 1><<<64, 256, 0, stream>>>(D_bf, t1T, s1T, s1);
    mm_mfma_kernel<1, 0><<<64, 256, 0, stream>>>(A_bf, s1T, t2T, (float*)nullptr);
    mm_mfma_kernel<0, 1><<<64, 256, 0, stream>>>(D_bf, t2T, (u16*)nullptr, s2);
    out1_kernel<<<(131072 + 255) / 256, 256, 0, stream>>>(sess, s1, s2, out1, 131072);

    // ---- Part 3: GNN (bf16 MFMA): gemm1 + fused einsum/gates per half ----
    gemm1_kernel<<<512, 256, 0, stream>>>(hidden, W_in_bf, W_out_bf, b_in, b_out, hT, 0);
    gnn_tail_kernel<<<512, 256, 0, stream>>>(hT, A_gnn, alias_pos, b_iah, b_oah, hidden,
                                             w_ih_bf, b_ih, w_hh_bf, b_hh, out2, 0);
    gemm1_kernel<<<512, 256, 0, stream>>>(hidden, W_in_bf, W_out_bf, b_in, b_out, hT, 512);
    gnn_tail_kernel<<<512, 256, 0, stream>>>(hT, A_gnn, alias_pos, b_iah, b_oah, hidden,
                                             w_ih_bf, b_ih, w_hh_bf, b_hh, out2, 512);
}

// Round 2
// 376.577 us; speedup vs baseline: 1.0724x; 1.0351x over previous
//
#include <hip/hip_runtime.h>

#define EMB 128
#define NN 50000
#define BB 1024
#define LL 50
#define NBK 49     // ceil(NN/1024) buckets
#define NEB 512    // emit/count chunks

typedef float f32x4 __attribute__((ext_vector_type(4)));
typedef float f32x2 __attribute__((ext_vector_type(2)));
typedef unsigned short u16;
typedef unsigned int u32;
typedef unsigned long long u64;
typedef u16 u16x4 __attribute__((ext_vector_type(4)));
typedef u32 u32x4 __attribute__((ext_vector_type(4)));
typedef short bf16x8 __attribute__((ext_vector_type(8)));   // 8 bf16 in 4 VGPRs

__device__ __forceinline__ float u2f(u16 u) {
    union { unsigned int i; float f; } v; v.i = ((unsigned int)u) << 16; return v.f;
}
__device__ __forceinline__ u16 f2b(float f) {
    union { float f; unsigned int i; } v; v.f = f;
    unsigned int i = v.i;
    return (u16)((i + 0x7FFFu + ((i >> 16) & 1u)) >> 16);   // RNE
}
__device__ __forceinline__ float lo2f(u32 w) { return u2f((u16)(w & 0xffffu)); }
__device__ __forceinline__ float hi2f(u32 w) { return u2f((u16)(w >> 16)); }
__device__ __forceinline__ float sigmoidf_(float x) { return 1.f / (1.f + __expf(-x)); }

__device__ __forceinline__ bf16x8 ld_cvt8(const float* p) {
    f32x4 v0 = *(const f32x4*)p;
    f32x4 v1 = *(const f32x4*)(p + 4);
    union { u16 u[8]; bf16x8 b; } r;
#pragma unroll
    for (int t = 0; t < 4; t++) { r.u[t] = f2b(v0[t]); r.u[4 + t] = f2b(v1[t]); }
    return r.b;
}

// ================= prep: converts + per-(chunk,bucket) counts (LDS only) =================
__global__ __launch_bounds__(256) void prep_kernel(
    const float* __restrict__ emb, const float* __restrict__ A, const float* __restrict__ D,
    const float* __restrict__ wih, const float* __restrict__ whh,
    const float* __restrict__ Win, const float* __restrict__ Wout,
    u16* __restrict__ emb_bf, u16* __restrict__ A_bf, u16* __restrict__ D_bf,
    u16* __restrict__ wih_bf, u16* __restrict__ whh_bf,
    u16* __restrict__ Win_bf, u16* __restrict__ Wout_bf,
    const int* __restrict__ rowi, int* __restrict__ bcnt,
    int E, int chunk)
{
    __shared__ int lc[NBK];
    int gid = blockIdx.x * 256 + threadIdx.x;
    int stride = gridDim.x * 256;
    int tid = threadIdx.x;
    if (blockIdx.x < NEB) {
        if (tid < NBK) lc[tid] = 0;
        __syncthreads();
        int beg = blockIdx.x * chunk, end = min(E, beg + chunk);
        for (int e = beg + tid; e < end; e += 256)
            atomicAdd(&lc[rowi[e] >> 10], 1);
        __syncthreads();
        if (tid < NBK) bcnt[blockIdx.x * NBK + tid] = lc[tid];
    }
    for (int i = gid; i < 1600000; i += stride) {
        f32x4 v = *(const f32x4*)(emb + (size_t)i * 4);
        u16x4 p;
#pragma unroll
        for (int t = 0; t < 4; t++) p[t] = f2b(v[t]);
        *(u16x4*)(emb_bf + (size_t)i * 4) = p;
    }
    for (int i = gid; i < 2277376; i += stride) {
        const float* s; u16* d; int off;
        if (i < 1048576)      { s = A;    d = A_bf;    off = i; }
        else if (i < 2097152) { s = D;    d = D_bf;    off = i - 1048576; }
        else if (i < 2195456) { s = wih;  d = wih_bf;  off = i - 2097152; }
        else if (i < 2244608) { s = whh;  d = whh_bf;  off = i - 2195456; }
        else if (i < 2260992) { s = Win;  d = Win_bf;  off = i - 2244608; }
        else                  { s = Wout; d = Wout_bf; off = i - 2260992; }
        d[off] = f2b(s[off]);
    }
}

// per-bucket exclusive scan over chunks -> LOCAL bases + bucket totals
__global__ __launch_bounds__(512) void bktscan_kernel(
    const int* __restrict__ bcnt, int* __restrict__ sofs, int* __restrict__ btot)
{
    __shared__ int ps[512];
    int k = blockIdx.x, t = threadIdx.x;
    int c = bcnt[t * NBK + k];
    ps[t] = c; __syncthreads();
    for (int off = 1; off < 512; off <<= 1) {
        int v = (t >= off) ? ps[t - off] : 0;
        __syncthreads();
        ps[t] += v; __syncthreads();
    }
    sofs[t * NBK + k] = ps[t] - c;
    if (t == 511) btot[k] = ps[511];
}

__global__ __launch_bounds__(64) void btotal_kernel(
    const int* __restrict__ btot, int* __restrict__ bofs, int E)
{
    if (threadIdx.x == 0) {
        int run = 0;
        for (int k = 0; k < NBK; k++) { bofs[k] = run; run += btot[k]; }
        bofs[NBK] = E;
    }
}

__global__ __launch_bounds__(256) void emit_kernel(
    const int* __restrict__ rowi, const int* __restrict__ coli, const float* __restrict__ val,
    const int* __restrict__ sofs, const int* __restrict__ bofs,
    u64* __restrict__ egs, int E, int chunk)
{
    __shared__ int cur[NBK];
    int b = blockIdx.x, tid = threadIdx.x;
    if (tid < NBK) cur[tid] = bofs[tid] + sofs[b * NBK + tid];
    __syncthreads();
    int beg = b * chunk, end = min(E, beg + chunk);
    for (int e = beg + tid; e < end; e += 256) {
        int r = rowi[e];
        int slot = atomicAdd(&cur[r >> 10], 1);
        u64 entry = ((u64)(u32)(r & 1023) << 32)
                  | (u64)((u32)(u16)coli[e] | ((u32)f2b(val[e]) << 16));
        egs[slot] = entry;
    }
}

__global__ __launch_bounds__(1024) void binsort2_kernel(
    const u64* __restrict__ egs, const int* __restrict__ bofs,
    int* __restrict__ row_ptr, u32* __restrict__ eg, int E)
{
    __shared__ int cnt_s[1024];
    __shared__ int ps[1024];
    int k = blockIdx.x, tid = threadIdx.x;
    int r0 = k << 10;
    int beg = bofs[k], end = bofs[k + 1];
    cnt_s[tid] = 0;
    __syncthreads();
    for (int i = beg + tid; i < end; i += 1024)
        atomicAdd(&cnt_s[(int)(egs[i] >> 32)], 1);
    __syncthreads();
    int v = cnt_s[tid];
    ps[tid] = v; __syncthreads();
    for (int off = 1; off < 1024; off <<= 1) {
        int t = (tid >= off) ? ps[tid - off] : 0;
        __syncthreads();
        ps[tid] += t; __syncthreads();
    }
    int ex = beg + ps[tid] - v;
    if (r0 + tid <= NN) row_ptr[r0 + tid] = ex;
    if (k == NBK - 1 && tid == 1023) row_ptr[NN] = E;
    cnt_s[tid] = ex;
    __syncthreads();
    for (int i = beg + tid; i < end; i += 1024) {
        u64 entry = egs[i];
        int rlo = (int)(entry >> 32);
        int p = atomicAdd(&cnt_s[rlo], 1);
        eg[p] = (u32)entry;
    }
}

// One wave per row. 64 lanes = 4 edge-groups x 16 feature-blocks.
// Each lane loads dwordx4 (8 bf16 feats) per edge -> 4 edges per wave-instruction.
// 3-stage software pipeline: eg loads 2 pairs ahead, data loads 1 pair ahead.
// Tails handled by clamp + zero-val mask; cross-group reduce via shfl_xor(16/32).
template<int FUSE>
__global__ __launch_bounds__(256) void gatherb_kernel(
    const int* __restrict__ row_ptr, const u32* __restrict__ eg,
    const u16* __restrict__ src, const float* __restrict__ emb0,
    u16* __restrict__ dst_bf, float* __restrict__ dst_f)
{
    int wave = threadIdx.x >> 6;
    int lane = threadIdx.x & 63;
    int g  = lane >> 4;          // edge slot within chunk-of-4
    int fl = lane & 15;          // feature block: features fl*8 .. fl*8+7
    int r = blockIdx.x * 4 + wave;
    if (r >= NN) return;
    int beg = row_ptr[r], end = row_ptr[r + 1];

    float acc[8];
#pragma unroll
    for (int t = 0; t < 8; t++) acc[t] = 0.f;

    if (beg < end) {
        int last = end - 1;
        int npair = (end - beg + 7) >> 3;       // pairs of 4-edge chunks (8 edges)
        // S(0): eg for pair 0
        u32 pkA = eg[min(beg + g, last)];
        u32 pkB = eg[min(beg + 4 + g, last)];
        // X(0): data for pair 0
        float vA = (beg + g     < end) ? u2f((u16)(pkA >> 16)) : 0.f;
        float vB = (beg + 4 + g < end) ? u2f((u16)(pkB >> 16)) : 0.f;
        u32x4 xA = *(const u32x4*)(src + ((pkA & 0xffffu) << 7) + (fl << 3));
        u32x4 xB = *(const u32x4*)(src + ((pkB & 0xffffu) << 7) + (fl << 3));
        // S(1): eg for pair 1
        pkA = eg[min(beg + 8  + g, last)];
        pkB = eg[min(beg + 12 + g, last)];

        int e = beg;
        for (int p = 0; p < npair; p++) {
            // grab consume-ready pair p
            float cvA = vA, cvB = vB;
            u32x4 cxA = xA, cxB = xB;
            // X(p+1): issue data loads for next pair (safe clamped if past end)
            int eN = e + 8;
            vA = (eN + g     < end) ? u2f((u16)(pkA >> 16)) : 0.f;
            vB = (eN + 4 + g < end) ? u2f((u16)(pkB >> 16)) : 0.f;
            xA = *(const u32x4*)(src + ((pkA & 0xffffu) << 7) + (fl << 3));
            xB = *(const u32x4*)(src + ((pkB & 0xffffu) << 7) + (fl << 3));
            // S(p+2): issue eg loads two pairs ahead
            int eS = e + 16;
            pkA = eg[min(eS + g, last)];
            pkB = eg[min(eS + 4 + g, last)];
            // C(p): consume pair p
#pragma unroll
            for (int t = 0; t < 4; t++) {
                acc[2 * t]     += cvA * lo2f(cxA[t]);
                acc[2 * t + 1] += cvA * hi2f(cxA[t]);
            }
#pragma unroll
            for (int t = 0; t < 4; t++) {
                acc[2 * t]     += cvB * lo2f(cxB[t]);
                acc[2 * t + 1] += cvB * hi2f(cxB[t]);
            }
            e += 8;
        }
    }

    // reduce partial sums across the 4 edge-groups (lane bits 4 and 5)
#pragma unroll
    for (int t = 0; t < 8; t++) {
        acc[t] += __shfl_xor(acc[t], 16);
        acc[t] += __shfl_xor(acc[t], 32);
    }

    if (lane < 16) {
        if (FUSE) {
            u32x4 s = *(const u32x4*)(src + ((u32)r << 7) + (lane << 3));
            const float* e0p = emb0 + ((size_t)r << 7) + (lane << 3);
            f32x4 e0a = *(const f32x4*)e0p;
            f32x4 e0b = *(const f32x4*)(e0p + 4);
            f32x4 o0, o1;
#pragma unroll
            for (int t = 0; t < 2; t++) {
                o0[2 * t]     = acc[2 * t]     + e0a[2 * t]     + lo2f(s[t]);
                o0[2 * t + 1] = acc[2 * t + 1] + e0a[2 * t + 1] + hi2f(s[t]);
                o1[2 * t]     = acc[4 + 2 * t]     + e0b[2 * t]     + lo2f(s[2 + t]);
                o1[2 * t + 1] = acc[4 + 2 * t + 1] + e0b[2 * t + 1] + hi2f(s[2 + t]);
            }
            float* dp = dst_f + ((size_t)r << 7) + (lane << 3);
            *(f32x4*)dp = o0;
            *(f32x4*)(dp + 4) = o1;
        } else {
            u32x4 w;
#pragma unroll
            for (int t = 0; t < 4; t++)
                w[t] = (u32)f2b(acc[2 * t]) | ((u32)f2b(acc[2 * t + 1]) << 16);
            *(u32x4*)(dst_bf + ((size_t)r << 7) + (lane << 3)) = w;
        }
    }
}

// ================= Part 2: LineConv (bf16 MFMA chain) =================
__global__ __launch_bounds__(128) void sess_pool_kernel(
    const int* __restrict__ items, const float* __restrict__ emb,
    const float* __restrict__ slen, float* __restrict__ sess, u16* __restrict__ sessT)
{
    int b = blockIdx.x, d = threadIdx.x;
    const int* it = items + b * LL;
    float acc = 0.f;
    for (int l = 0; l < LL; l++) {
        int idx = it[l];
        if (idx > 0) acc += emb[(size_t)(idx - 1) * EMB + d];
    }
    float v = acc / slen[b];
    sess[b * EMB + d] = v;
    sessT[d * BB + b] = f2b(v);
}

// C[1024,128] = M_bf @ Xt_bf^T. 64 blocks x 4 waves; wave owns (16-row tile, 2 col-tiles).
template<int WT, int WF>
__global__ __launch_bounds__(256) void mm_mfma_kernel(
    const u16* __restrict__ M_bf, const u16* __restrict__ Xt_bf,
    u16* __restrict__ Ct_bf, float* __restrict__ C_f)
{
    int tid = threadIdx.x;
    int wv = tid >> 6, lane = tid & 63, cl = lane & 15, kg = lane >> 4;
    int rbase = blockIdx.x * 16;
    f32x4 acc[2];
    acc[0] = (f32x4)0.f; acc[1] = (f32x4)0.f;
    const u16* arow = M_bf + (size_t)(rbase + cl) * BB + kg * 8;
    const u16* brow = Xt_bf + (size_t)(wv * 32 + cl) * BB + kg * 8;   // col-tiles 2wv, 2wv+1
#pragma unroll 4
    for (int k0 = 0; k0 < BB; k0 += 32) {
        bf16x8 a  = *(const bf16x8*)(arow + k0);
        bf16x8 b0 = *(const bf16x8*)(brow + k0);
        bf16x8 b1 = *(const bf16x8*)(brow + (size_t)16 * BB + k0);
        acc[0] = __builtin_amdgcn_mfma_f32_16x16x32_bf16(a, b0, acc[0], 0, 0, 0);
        acc[1] = __builtin_amdgcn_mfma_f32_16x16x32_bf16(a, b1, acc[1], 0, 0, 0);
    }
#pragma unroll
    for (int nt = 0; nt < 2; nt++) {
        int col = (wv * 2 + nt) * 16 + cl;
#pragma unroll
        for (int j = 0; j < 4; j++) {
            int row = rbase + kg * 4 + j;
            if (WF) C_f[(size_t)row * EMB + col] = acc[nt][j];
            if (WT) Ct_bf[(size_t)col * BB + row] = f2b(acc[nt][j]);
        }
    }
}

__global__ __launch_bounds__(256) void out1_kernel(
    const float* __restrict__ a, const float* __restrict__ b,
    const float* __restrict__ c, float* __restrict__ o, int n)
{
    int i = blockIdx.x * 256 + threadIdx.x;
    if (i < n) o[i] = a[i] + b[i] + c[i];
}

// ================= Part 3: GNN (bf16 MFMA), fully fused per session =================
// Phase A: stage A_io -> AioHs.  Phase B: h_in/h_out = hidden @ W_in/W_out^T + b
// written TRANSPOSED straight into hTsXs (replaces the old gemm1+hT round-trip).
// Phase C: einsum. Phase D: inputs -> LDS, hidden -> AioHs. Phase E: gi/gh GEMMs.
// Phase F: GRU gates -> hy.
__global__ __launch_bounds__(256, 3) void gnn_tail_kernel(
    const float* __restrict__ hidden,
    const u16* __restrict__ W_in_bf, const u16* __restrict__ W_out_bf,
    const float* __restrict__ b_in, const float* __restrict__ b_out,
    const float* __restrict__ A_gnn, const int* __restrict__ alias_pos,
    const float* __restrict__ b_iah, const float* __restrict__ b_oah,
    const u16* __restrict__ w_ih_bf, const float* __restrict__ b_ih,
    const u16* __restrict__ w_hh_bf, const float* __restrict__ b_hh,
    float* __restrict__ hy)
{
    __shared__ __attribute__((aligned(16))) u16 AioHs[64 * 128];   // 16 KB
    __shared__ __attribute__((aligned(16))) u16 hTsXs[256 * 72];   // 36.9 KB
    int b = blockIdx.x;
    int tid = threadIdx.x;
    int wv = tid >> 6, lane = tid & 63, cl = lane & 15, kg = lane >> 4;

    // ---- Phase A: stage gathered A_io rows (bf16, swizzled) ----
    for (int i = tid; i < 64 * 32; i += 256) {
        int row = i >> 5, c4 = i & 31;
        u16x4 p = (u16x4)0;
        if (row < LL) {
            int pos = alias_pos[b * LL + row];
            const float* ar = A_gnn + ((size_t)b * LL + pos) * (2 * LL);
#pragma unroll
            for (int t = 0; t < 4; t++) {
                int jp = c4 * 4 + t;
                int col = (jp < 64) ? jp : (50 + (jp - 64));
                int ok = (jp < 64) ? (jp < LL) : ((jp - 64) < LL);
                if (ok) p[t] = f2b(ar[col]);
            }
        }
        *(u16x4*)((char*)AioHs + row * 256 + ((c4 * 8) ^ ((row & 7) << 4))) = p;
    }

    // ---- Phase B (fused gemm1): [h_in|h_out]^T -> hTsXs directly ----
    {
        const float* hsrc = hidden + (size_t)b * LL * EMB;
        int mr = wv * 16 + cl;
        f32x4 acc1[16];
#pragma unroll
        for (int nt = 0; nt < 16; nt++) acc1[nt] = (f32x4)0.f;
#pragma unroll
        for (int ks = 0; ks < 4; ks++) {
            int k0 = ks * 32;
            bf16x8 a = (mr < LL) ? ld_cvt8(hsrc + mr * 128 + k0 + kg * 8) : (bf16x8)0;
#pragma unroll
            for (int nt = 0; nt < 16; nt++) {
                const u16* wsrc = (nt < 8) ? W_in_bf : W_out_bf;
                int wr = (nt & 7) * 16 + cl;
                bf16x8 bf = *(const bf16x8*)(wsrc + (size_t)wr * 128 + k0 + kg * 8);
                acc1[nt] = __builtin_amdgcn_mfma_f32_16x16x32_bf16(a, bf, acc1[nt], 0, 0, 0);
            }
        }
#pragma unroll
        for (int nt = 0; nt < 16; nt++) {
            int col = nt * 16 + cl;
            float bias = (col < 128) ? b_in[col] : b_out[col - 128];
            int r0 = wv * 16 + kg * 4;
            u16x4 p;
#pragma unroll
            for (int j = 0; j < 4; j++)
                p[j] = (r0 + j < LL) ? f2b(acc1[nt][j] + bias) : (u16)0;
            *(u16x4*)&hTsXs[col * 72 + r0] = p;
        }
    }
    __syncthreads();

    // ---- Phase C: einsum inputs = A_io @ [h_in|h_out] ----
    f32x4 acc[16];
#pragma unroll
    for (int nt = 0; nt < 16; nt++) acc[nt] = (f32x4)0.f;
#pragma unroll
    for (int ks = 0; ks < 2; ks++) {
#pragma unroll
        for (int nt = 0; nt < 16; nt++) {
            int koff = (nt < 8) ? 0 : 64;
            int k0 = koff + ks * 32;
            int mr = wv * 16 + cl;
            bf16x8 a = *(const bf16x8*)((const char*)AioHs + mr * 256 +
                        (((k0 << 1) + (kg << 4)) ^ ((mr & 7) << 4)));
            bf16x8 bf = *(const bf16x8*)&hTsXs[(nt * 16 + cl) * 72 + ks * 32 + kg * 8];
            acc[nt] = __builtin_amdgcn_mfma_f32_16x16x32_bf16(a, bf, acc[nt], 0, 0, 0);
        }
    }
    __syncthreads();

    // ---- Phase D: inputs -> hTsXs (swizzled), hidden -> AioHs (bf16) ----
#pragma unroll
    for (int nt = 0; nt < 16; nt++) {
        int dp = nt * 16 + cl;
        float bias = (dp < 128) ? b_iah[dp] : b_oah[dp - 128];
#pragma unroll
        for (int j = 0; j < 4; j++) {
            int i = wv * 16 + kg * 4 + j;
            *(u16*)((char*)hTsXs + i * 512 + ((dp * 2) ^ ((i & 7) << 4))) =
                f2b(acc[nt][j] + bias);
        }
    }
    const float* hsrc = hidden + (size_t)b * LL * EMB;
#pragma unroll
    for (int i2 = 0; i2 < 8; i2++) {
        int lin = i2 * 256 + tid;
        int row = lin >> 5, c4 = lin & 31;
        u16x4 p = (u16x4)0;
        if (row < LL) {
            f32x4 v = *(const f32x4*)(hsrc + row * 128 + c4 * 4);
#pragma unroll
            for (int t = 0; t < 4; t++) p[t] = f2b(v[t]);
        }
        *(u16x4*)((char*)AioHs + row * 256 + ((c4 * 8) ^ ((row & 7) << 4))) = p;
    }
    __syncthreads();

    // ---- Phase E: gi = inputs @ w_ih^T, gh = hidden @ w_hh^T ----
    f32x4 acc_ri[4][2][2];
    f32x4 acc_n1[4][2];
    f32x4 acc_n2[4][2];
#pragma unroll
    for (int mt = 0; mt < 4; mt++)
#pragma unroll
        for (int t = 0; t < 2; t++) {
            acc_ri[mt][0][t] = (f32x4)0.f; acc_ri[mt][1][t] = (f32x4)0.f;
            acc_n1[mt][t] = (f32x4)0.f; acc_n2[mt][t] = (f32x4)0.f;
        }

#pragma unroll
    for (int ks = 0; ks < 8; ks++) {
        int k0 = ks * 32;
        bf16x8 a[4];
#pragma unroll
        for (int mt = 0; mt < 4; mt++) {
            int mr = mt * 16 + cl;
            a[mt] = *(const bf16x8*)((const char*)hTsXs + mr * 512 +
                     (((k0 << 1) + (kg << 4)) ^ ((mr & 7) << 4)));
        }
#pragma unroll
        for (int g = 0; g < 3; g++)
#pragma unroll
            for (int t = 0; t < 2; t++) {
                int brow = g * 128 + wv * 32 + t * 16 + cl;
                bf16x8 bw = *(const bf16x8*)(w_ih_bf + (size_t)brow * 256 + k0 + kg * 8);
#pragma unroll
                for (int mt = 0; mt < 4; mt++) {
                    f32x4* dst = (g < 2) ? &acc_ri[mt][g][t] : &acc_n1[mt][t];
                    *dst = __builtin_amdgcn_mfma_f32_16x16x32_bf16(a[mt], bw, *dst, 0, 0, 0);
                }
            }
    }
#pragma unroll
    for (int ks = 0; ks < 4; ks++) {
        int k0 = ks * 32;
        bf16x8 a[4];
#pragma unroll
        for (int mt = 0; mt < 4; mt++) {
            int mr = mt * 16 + cl;
            a[mt] = *(const bf16x8*)((const char*)AioHs + mr * 256 +
                     (((k0 << 1) + (kg << 4)) ^ ((mr & 7) << 4)));
        }
#pragma unroll
        for (int g = 0; g < 3; g++)
#pragma unroll
            for (int t = 0; t < 2; t++) {
                int brow = g * 128 + wv * 32 + t * 16 + cl;
                bf16x8 bw = *(const bf16x8*)(w_hh_bf + (size_t)brow * 128 + k0 + kg * 8);
#pragma unroll
                for (int mt = 0; mt < 4; mt++) {
                    f32x4* dst = (g < 2) ? &acc_ri[mt][g][t] : &acc_n2[mt][t];
                    *dst = __builtin_amdgcn_mfma_f32_16x16x32_bf16(a[mt], bw, *dst, 0, 0, 0);
                }
            }
    }

    // ---- Phase F: GRU gates ----
#pragma unroll
    for (int t = 0; t < 2; t++) {
        int d = wv * 32 + t * 16 + cl;
        float br = b_ih[d] + b_hh[d];
        float bi = b_ih[128 + d] + b_hh[128 + d];
        float bn1 = b_ih[256 + d], bn2 = b_hh[256 + d];
#pragma unroll
        for (int mt = 0; mt < 4; mt++)
#pragma unroll
            for (int j = 0; j < 4; j++) {
                int row = mt * 16 + kg * 4 + j;
                if (row >= LL) continue;
                float rg = sigmoidf_(acc_ri[mt][0][t][j] + br);
                float ig = sigmoidf_(acc_ri[mt][1][t][j] + bi);
                float ng = tanhf(acc_n1[mt][t][j] + bn1 + rg * (acc_n2[mt][t][j] + bn2));
                u16 hb = *(const u16*)((const char*)AioHs + row * 256 + ((d * 2) ^ ((row & 7) << 4)));
                float h = u2f(hb);
                hy[((size_t)b * LL + row) * 128 + d] = ng + ig * (h - ng);
            }
    }
}

extern "C" void kernel_launch(void* const* d_in, const int* in_sizes, int n_in,
                              void* d_out, int out_size, void* d_ws, size_t ws_size,
                              hipStream_t stream) {
    (void)n_in; (void)out_size; (void)ws_size;
    const int*   adj_row      = (const int*)d_in[0];
    const int*   adj_col      = (const int*)d_in[1];
    const float* adj_val      = (const float*)d_in[2];
    const float* embedding    = (const float*)d_in[3];
    const int*   session_item = (const int*)d_in[4];
    const float* session_len  = (const float*)d_in[5];
    const float* Dm           = (const float*)d_in[6];
    const float* A_sess       = (const float*)d_in[7];
    const float* A_gnn        = (const float*)d_in[8];
    const int*   alias_pos    = (const int*)d_in[9];
    const float* hidden       = (const float*)d_in[10];
    const float* W_in         = (const float*)d_in[11];
    const float* b_in         = (const float*)d_in[12];
    const float* W_out        = (const float*)d_in[13];
    const float* b_out        = (const float*)d_in[14];
    const float* w_ih         = (const float*)d_in[15];
    const float* b_ih         = (const float*)d_in[16];
    const float* w_hh         = (const float*)d_in[17];
    const float* b_hh         = (const float*)d_in[18];
    const float* b_iah        = (const float*)d_in[19];
    const float* b_oah        = (const float*)d_in[20];
    const int E = in_sizes[0];

    float* out0 = (float*)d_out;
    float* out1 = out0 + 6400000;
    float* out2 = out1 + 131072;

    float* ws = (float*)d_ws;
    u16*  emb_bf  = (u16*)ws;                    // [0, 3.2M) live through gathers
    int*  bcnt  = (int*)(ws + 3200000);          // scratch under accA region
    int*  sofs  = (int*)(ws + 3230000);
    int*  btot  = (int*)(ws + 3260000);
    u16*  accA_bf = (u16*)(ws + 3200000);        // [3.2M, 6.4M) gather<0> out
    u32*  eg    = (u32*)(ws + 6400000);          // [6.4M, 8.0M)
    u64*  egs   = (u64*)(ws + 8000000);          // [8.0M, 11.2M)
    float* sess  = ws + 11200000;
    u16*   sessT = (u16*)(ws + 11350000);
    u16*   t1T   = (u16*)(ws + 11400000);
    u16*   s1T   = (u16*)(ws + 11450000);
    u16*   t2T   = (u16*)(ws + 11500000);
    float* s1    = ws + 11550000;
    float* s2    = ws + 11700000;
    u16*   A_bf  = (u16*)(ws + 11850000);
    u16*   D_bf  = (u16*)(ws + 12400000);
    int*   row_ptr = (int*)(ws + 12950000);
    int*   bofs    = row_ptr + NN + 1;
    u16* w_ih_bf   = (u16*)(ws + 13107200);
    u16* w_hh_bf   = w_ih_bf + 98304;
    u16* W_in_bf   = w_hh_bf + 49152;
    u16* W_out_bf  = W_in_bf + 16384;

    int chunk = (E + NEB - 1) / NEB;

    // ---- prep: converts + chunked bucket counts (no global atomics) ----
    prep_kernel<<<2048, 256, 0, stream>>>(embedding, A_sess, Dm, w_ih, w_hh, W_in, W_out,
                                          emb_bf, A_bf, D_bf, w_ih_bf, w_hh_bf, W_in_bf, W_out_bf,
                                          adj_row, bcnt, E, chunk);

    // ---- Part 1: bucket sort + 2 bf16 gather layers ----
    bktscan_kernel<<<NBK, 512, 0, stream>>>(bcnt, sofs, btot);
    btotal_kernel<<<1, 64, 0, stream>>>(btot, bofs, E);
    emit_kernel<<<NEB, 256, 0, stream>>>(adj_row, adj_col, adj_val, sofs, bofs, egs, E, chunk);
    binsort2_kernel<<<NBK, 1024, 0, stream>>>(egs, bofs, row_ptr, eg, E);
    gatherb_kernel<0><<<(NN + 3) / 4, 256, 0, stream>>>(row_ptr, eg, emb_bf, embedding, accA_bf, (float*)nullptr);
    gatherb_kernel<1><<<(NN + 3) / 4, 256, 0, stream>>>(row_ptr, eg, accA_bf, embedding, (u16*)nullptr, out0);

    // ---- Part 2: LineConv (MFMA chain, re-associated s_next = D @ (A @ s)) ----
    sess_pool_kernel<<<BB, 128, 0, stream>>>(session_item, embedding, session_len, sess, sessT);
    mm_mfma_kernel<1, 0><<<64, 256, 0, stream>>>(A_bf, sessT, t1T, (float*)nullptr);
    mm_mfma_kernel<1, 1><<<64, 256, 0, stream>>>(D_bf, t1T, s1T, s1);
    mm_mfma_kernel<1, 0><<<64, 256, 0, stream>>>(A_bf, s1T, t2T, (float*)nullptr);
    mm_mfma_kernel<0, 1><<<64, 256, 0, stream>>>(D_bf, t2T, (u16*)nullptr, s2);
    out1_kernel<<<(131072 + 255) / 256, 256, 0, stream>>>(sess, s1, s2, out1, 131072);

    // ---- Part 3: GNN fully fused, one dispatch over all 1024 sessions ----
    gnn_tail_kernel<<<BB, 256, 0, stream>>>(hidden, W_in_bf, W_out_bf, b_in, b_out,
                                            A_gnn, alias_pos, b_iah, b_oah,
                                            w_ih_bf, b_ih, w_hh_bf, b_hh, out2);
}

// Round 3
// 327.474 us; speedup vs baseline: 1.2332x; 1.1499x over previous
//
#include <hip/hip_runtime.h>

#define EMB 128
#define NN 50000
#define BB 1024
#define LL 50
#define NBK 49     // ceil(NN/1024) buckets
#define NEB 512    // emit/count chunks

typedef float f32x4 __attribute__((ext_vector_type(4)));
typedef float f32x2 __attribute__((ext_vector_type(2)));
typedef unsigned short u16;
typedef unsigned int u32;
typedef unsigned long long u64;
typedef u16 u16x4 __attribute__((ext_vector_type(4)));
typedef u32 u32x4 __attribute__((ext_vector_type(4)));
typedef short bf16x8 __attribute__((ext_vector_type(8)));   // 8 bf16 in 4 VGPRs

__device__ __forceinline__ float u2f(u16 u) {
    union { unsigned int i; float f; } v; v.i = ((unsigned int)u) << 16; return v.f;
}
__device__ __forceinline__ u16 f2b(float f) {
    union { float f; unsigned int i; } v; v.f = f;
    unsigned int i = v.i;
    return (u16)((i + 0x7FFFu + ((i >> 16) & 1u)) >> 16);   // RNE
}
__device__ __forceinline__ float lo2f(u32 w) { return u2f((u16)(w & 0xffffu)); }
__device__ __forceinline__ float hi2f(u32 w) { return u2f((u16)(w >> 16)); }
__device__ __forceinline__ float sigmoidf_(float x) { return 1.f / (1.f + __expf(-x)); }

__device__ __forceinline__ bf16x8 ld_cvt8(const float* p) {
    f32x4 v0 = *(const f32x4*)p;
    f32x4 v1 = *(const f32x4*)(p + 4);
    union { u16 u[8]; bf16x8 b; } r;
#pragma unroll
    for (int t = 0; t < 4; t++) { r.u[t] = f2b(v0[t]); r.u[4 + t] = f2b(v1[t]); }
    return r.b;
}

// ================= prep: converts + per-(chunk,bucket) counts (LDS only) =================
__global__ __launch_bounds__(256) void prep_kernel(
    const float* __restrict__ emb, const float* __restrict__ A, const float* __restrict__ D,
    const float* __restrict__ wih, const float* __restrict__ whh,
    const float* __restrict__ Win, const float* __restrict__ Wout,
    u16* __restrict__ emb_bf, u16* __restrict__ A_bf, u16* __restrict__ D_bf,
    u16* __restrict__ wih_bf, u16* __restrict__ whh_bf,
    u16* __restrict__ Win_bf, u16* __restrict__ Wout_bf,
    const int* __restrict__ rowi, int* __restrict__ bcnt,
    int E, int chunk)
{
    __shared__ int lc[NBK];
    int gid = blockIdx.x * 256 + threadIdx.x;
    int stride = gridDim.x * 256;
    int tid = threadIdx.x;
    if (blockIdx.x < NEB) {
        if (tid < NBK) lc[tid] = 0;
        __syncthreads();
        int beg = blockIdx.x * chunk, end = min(E, beg + chunk);
        for (int e = beg + tid; e < end; e += 256)
            atomicAdd(&lc[rowi[e] >> 10], 1);
        __syncthreads();
        if (tid < NBK) bcnt[blockIdx.x * NBK + tid] = lc[tid];
    }
    for (int i = gid; i < 1600000; i += stride) {
        f32x4 v = *(const f32x4*)(emb + (size_t)i * 4);
        u16x4 p;
#pragma unroll
        for (int t = 0; t < 4; t++) p[t] = f2b(v[t]);
        *(u16x4*)(emb_bf + (size_t)i * 4) = p;
    }
    for (int i = gid; i < 2277376; i += stride) {
        const float* s; u16* d; int off;
        if (i < 1048576)      { s = A;    d = A_bf;    off = i; }
        else if (i < 2097152) { s = D;    d = D_bf;    off = i - 1048576; }
        else if (i < 2195456) { s = wih;  d = wih_bf;  off = i - 2097152; }
        else if (i < 2244608) { s = whh;  d = whh_bf;  off = i - 2195456; }
        else if (i < 2260992) { s = Win;  d = Win_bf;  off = i - 2244608; }
        else                  { s = Wout; d = Wout_bf; off = i - 2260992; }
        d[off] = f2b(s[off]);
    }
}

// per-bucket exclusive scan over chunks -> LOCAL bases + bucket totals
__global__ __launch_bounds__(512) void bktscan_kernel(
    const int* __restrict__ bcnt, int* __restrict__ sofs, int* __restrict__ btot)
{
    __shared__ int ps[512];
    int k = blockIdx.x, t = threadIdx.x;
    int c = bcnt[t * NBK + k];
    ps[t] = c; __syncthreads();
    for (int off = 1; off < 512; off <<= 1) {
        int v = (t >= off) ? ps[t - off] : 0;
        __syncthreads();
        ps[t] += v; __syncthreads();
    }
    sofs[t * NBK + k] = ps[t] - c;
    if (t == 511) btot[k] = ps[511];
}

__global__ __launch_bounds__(64) void btotal_kernel(
    const int* __restrict__ btot, int* __restrict__ bofs, int E)
{
    if (threadIdx.x == 0) {
        int run = 0;
        for (int k = 0; k < NBK; k++) { bofs[k] = run; run += btot[k]; }
        bofs[NBK] = E;
    }
}

__global__ __launch_bounds__(256) void emit_kernel(
    const int* __restrict__ rowi, const int* __restrict__ coli, const float* __restrict__ val,
    const int* __restrict__ sofs, const int* __restrict__ bofs,
    u64* __restrict__ egs, int E, int chunk)
{
    __shared__ int cur[NBK];
    int b = blockIdx.x, tid = threadIdx.x;
    if (tid < NBK) cur[tid] = bofs[tid] + sofs[b * NBK + tid];
    __syncthreads();
    int beg = b * chunk, end = min(E, beg + chunk);
    for (int e = beg + tid; e < end; e += 256) {
        int r = rowi[e];
        int slot = atomicAdd(&cur[r >> 10], 1);
        u64 entry = ((u64)(u32)(r & 1023) << 32)
                  | (u64)((u32)(u16)coli[e] | ((u32)f2b(val[e]) << 16));
        egs[slot] = entry;
    }
}

__global__ __launch_bounds__(1024) void binsort2_kernel(
    const u64* __restrict__ egs, const int* __restrict__ bofs,
    int* __restrict__ row_ptr, u32* __restrict__ eg, int E)
{
    __shared__ int cnt_s[1024];
    __shared__ int ps[1024];
    int k = blockIdx.x, tid = threadIdx.x;
    int r0 = k << 10;
    int beg = bofs[k], end = bofs[k + 1];
    cnt_s[tid] = 0;
    __syncthreads();
    for (int i = beg + tid; i < end; i += 1024)
        atomicAdd(&cnt_s[(int)(egs[i] >> 32)], 1);
    __syncthreads();
    int v = cnt_s[tid];
    ps[tid] = v; __syncthreads();
    for (int off = 1; off < 1024; off <<= 1) {
        int t = (tid >= off) ? ps[tid - off] : 0;
        __syncthreads();
        ps[tid] += t; __syncthreads();
    }
    int ex = beg + ps[tid] - v;
    if (r0 + tid <= NN) row_ptr[r0 + tid] = ex;
    if (k == NBK - 1 && tid == 1023) row_ptr[NN] = E;
    cnt_s[tid] = ex;
    __syncthreads();
    for (int i = beg + tid; i < end; i += 1024) {
        u64 entry = egs[i];
        int rlo = (int)(entry >> 32);
        int p = atomicAdd(&cnt_s[rlo], 1);
        eg[p] = (u32)entry;
    }
}

// One wave per row. 64 lanes = 4 edge-groups x 16 feature-blocks.
// Each lane loads dwordx4 (8 bf16 feats) per edge -> 4 edges per wave-instruction.
// 3-stage software pipeline: eg loads 2 pairs ahead, data loads 1 pair ahead.
// Tails handled by clamp + zero-val mask; cross-group reduce via shfl_xor(16/32).
template<int FUSE>
__global__ __launch_bounds__(256) void gatherb_kernel(
    const int* __restrict__ row_ptr, const u32* __restrict__ eg,
    const u16* __restrict__ src, const float* __restrict__ emb0,
    u16* __restrict__ dst_bf, float* __restrict__ dst_f)
{
    int wave = threadIdx.x >> 6;
    int lane = threadIdx.x & 63;
    int g  = lane >> 4;          // edge slot within chunk-of-4
    int fl = lane & 15;          // feature block: features fl*8 .. fl*8+7
    int r = blockIdx.x * 4 + wave;
    if (r >= NN) return;
    int beg = row_ptr[r], end = row_ptr[r + 1];

    float acc[8];
#pragma unroll
    for (int t = 0; t < 8; t++) acc[t] = 0.f;

    if (beg < end) {
        int last = end - 1;
        int npair = (end - beg + 7) >> 3;       // pairs of 4-edge chunks (8 edges)
        // S(0): eg for pair 0
        u32 pkA = eg[min(beg + g, last)];
        u32 pkB = eg[min(beg + 4 + g, last)];
        // X(0): data for pair 0
        float vA = (beg + g     < end) ? u2f((u16)(pkA >> 16)) : 0.f;
        float vB = (beg + 4 + g < end) ? u2f((u16)(pkB >> 16)) : 0.f;
        u32x4 xA = *(const u32x4*)(src + ((pkA & 0xffffu) << 7) + (fl << 3));
        u32x4 xB = *(const u32x4*)(src + ((pkB & 0xffffu) << 7) + (fl << 3));
        // S(1): eg for pair 1
        pkA = eg[min(beg + 8  + g, last)];
        pkB = eg[min(beg + 12 + g, last)];

        int e = beg;
        for (int p = 0; p < npair; p++) {
            // grab consume-ready pair p
            float cvA = vA, cvB = vB;
            u32x4 cxA = xA, cxB = xB;
            // X(p+1): issue data loads for next pair (safe clamped if past end)
            int eN = e + 8;
            vA = (eN + g     < end) ? u2f((u16)(pkA >> 16)) : 0.f;
            vB = (eN + 4 + g < end) ? u2f((u16)(pkB >> 16)) : 0.f;
            xA = *(const u32x4*)(src + ((pkA & 0xffffu) << 7) + (fl << 3));
            xB = *(const u32x4*)(src + ((pkB & 0xffffu) << 7) + (fl << 3));
            // S(p+2): issue eg loads two pairs ahead
            int eS = e + 16;
            pkA = eg[min(eS + g, last)];
            pkB = eg[min(eS + 4 + g, last)];
            // C(p): consume pair p
#pragma unroll
            for (int t = 0; t < 4; t++) {
                acc[2 * t]     += cvA * lo2f(cxA[t]);
                acc[2 * t + 1] += cvA * hi2f(cxA[t]);
            }
#pragma unroll
            for (int t = 0; t < 4; t++) {
                acc[2 * t]     += cvB * lo2f(cxB[t]);
                acc[2 * t + 1] += cvB * hi2f(cxB[t]);
            }
            e += 8;
        }
    }

    // reduce partial sums across the 4 edge-groups (lane bits 4 and 5)
#pragma unroll
    for (int t = 0; t < 8; t++) {
        acc[t] += __shfl_xor(acc[t], 16);
        acc[t] += __shfl_xor(acc[t], 32);
    }

    if (lane < 16) {
        if (FUSE) {
            u32x4 s = *(const u32x4*)(src + ((u32)r << 7) + (lane << 3));
            const float* e0p = emb0 + ((size_t)r << 7) + (lane << 3);
            f32x4 e0a = *(const f32x4*)e0p;
            f32x4 e0b = *(const f32x4*)(e0p + 4);
            f32x4 o0, o1;
#pragma unroll
            for (int t = 0; t < 2; t++) {
                o0[2 * t]     = acc[2 * t]     + e0a[2 * t]     + lo2f(s[t]);
                o0[2 * t + 1] = acc[2 * t + 1] + e0a[2 * t + 1] + hi2f(s[t]);
                o1[2 * t]     = acc[4 + 2 * t]     + e0b[2 * t]     + lo2f(s[2 + t]);
                o1[2 * t + 1] = acc[4 + 2 * t + 1] + e0b[2 * t + 1] + hi2f(s[2 + t]);
            }
            float* dp = dst_f + ((size_t)r << 7) + (lane << 3);
            *(f32x4*)dp = o0;
            *(f32x4*)(dp + 4) = o1;
        } else {
            u32x4 w;
#pragma unroll
            for (int t = 0; t < 4; t++)
                w[t] = (u32)f2b(acc[2 * t]) | ((u32)f2b(acc[2 * t + 1]) << 16);
            *(u32x4*)(dst_bf + ((size_t)r << 7) + (lane << 3)) = w;
        }
    }
}

// ================= Part 2: LineConv (bf16 MFMA chain) =================
__global__ __launch_bounds__(128) void sess_pool_kernel(
    const int* __restrict__ items, const float* __restrict__ emb,
    const float* __restrict__ slen, float* __restrict__ sess, u16* __restrict__ sessT)
{
    int b = blockIdx.x, d = threadIdx.x;
    const int* it = items + b * LL;
    float acc = 0.f;
    for (int l = 0; l < LL; l++) {
        int idx = it[l];
        if (idx > 0) acc += emb[(size_t)(idx - 1) * EMB + d];
    }
    float v = acc / slen[b];
    sess[b * EMB + d] = v;
    sessT[d * BB + b] = f2b(v);
}

// C[1024,128] = M_bf @ Xt_bf^T. 64 blocks x 4 waves; wave owns (16-row tile, 2 col-tiles).
template<int WT, int WF>
__global__ __launch_bounds__(256) void mm_mfma_kernel(
    const u16* __restrict__ M_bf, const u16* __restrict__ Xt_bf,
    u16* __restrict__ Ct_bf, float* __restrict__ C_f)
{
    int tid = threadIdx.x;
    int wv = tid >> 6, lane = tid & 63, cl = lane & 15, kg = lane >> 4;
    int rbase = blockIdx.x * 16;
    f32x4 acc[2];
    acc[0] = (f32x4)0.f; acc[1] = (f32x4)0.f;
    const u16* arow = M_bf + (size_t)(rbase + cl) * BB + kg * 8;
    const u16* brow = Xt_bf + (size_t)(wv * 32 + cl) * BB + kg * 8;   // col-tiles 2wv, 2wv+1
#pragma unroll 4
    for (int k0 = 0; k0 < BB; k0 += 32) {
        bf16x8 a  = *(const bf16x8*)(arow + k0);
        bf16x8 b0 = *(const bf16x8*)(brow + k0);
        bf16x8 b1 = *(const bf16x8*)(brow + (size_t)16 * BB + k0);
        acc[0] = __builtin_amdgcn_mfma_f32_16x16x32_bf16(a, b0, acc[0], 0, 0, 0);
        acc[1] = __builtin_amdgcn_mfma_f32_16x16x32_bf16(a, b1, acc[1], 0, 0, 0);
    }
#pragma unroll
    for (int nt = 0; nt < 2; nt++) {
        int col = (wv * 2 + nt) * 16 + cl;
#pragma unroll
        for (int j = 0; j < 4; j++) {
            int row = rbase + kg * 4 + j;
            if (WF) C_f[(size_t)row * EMB + col] = acc[nt][j];
            if (WT) Ct_bf[(size_t)col * BB + row] = f2b(acc[nt][j]);
        }
    }
}

__global__ __launch_bounds__(256) void out1_kernel(
    const float* __restrict__ a, const float* __restrict__ b,
    const float* __restrict__ c, float* __restrict__ o, int n)
{
    int i = blockIdx.x * 256 + threadIdx.x;
    if (i < n) o[i] = a[i] + b[i] + c[i];
}

// ================= Part 3: GNN (bf16 MFMA), fully fused per session, 8 waves =================
// Waves split: wr = wv&3 selects the 16-row tile, wh = wv>>2 selects the nt/col half.
// Phase A': prefetch A_io into regs (loads in flight across Phase B).
// Phase B: h_in/h_out = hidden @ W^T + b, written transposed into hTsXs (LDS).
// Phase C: einsum. Phase D: inputs -> hTsXs (swizzled), hidden -> AioHs.
// Phase E: gi/gh GEMMs (d split 8 ways -> 64 acc floats/lane, no spill).
// Phase F: GRU gates -> hy.
__global__ __launch_bounds__(512) void gnn_tail_kernel(
    const float* __restrict__ hidden,
    const u16* __restrict__ W_in_bf, const u16* __restrict__ W_out_bf,
    const float* __restrict__ b_in, const float* __restrict__ b_out,
    const float* __restrict__ A_gnn, const int* __restrict__ alias_pos,
    const float* __restrict__ b_iah, const float* __restrict__ b_oah,
    const u16* __restrict__ w_ih_bf, const float* __restrict__ b_ih,
    const u16* __restrict__ w_hh_bf, const float* __restrict__ b_hh,
    float* __restrict__ hy)
{
    __shared__ __attribute__((aligned(16))) u16 AioHs[64 * 128];   // 16 KB
    __shared__ __attribute__((aligned(16))) u16 hTsXs[256 * 72];   // 36.9 KB
    int b = blockIdx.x;
    int tid = threadIdx.x;
    int wv = tid >> 6, lane = tid & 63, cl = lane & 15, kg = lane >> 4;
    int wr = wv & 3;     // row-tile selector
    int wh = wv >> 2;    // col-half selector

    // ---- Phase A': issue A_io gather into regs (2048 items / 512 thr = 4 each) ----
    int pr_row[4], pr_c4[4], ppos[4];
#pragma unroll
    for (int it = 0; it < 4; it++) {
        int i = tid + it * 512;
        pr_row[it] = i >> 5; pr_c4[it] = i & 31;
        ppos[it] = (pr_row[it] < LL) ? alias_pos[b * LL + pr_row[it]] : 0;
    }
    float av[4][4];
#pragma unroll
    for (int it = 0; it < 4; it++) {
        const float* ar = A_gnn + ((size_t)b * LL + ppos[it]) * (2 * LL);
#pragma unroll
        for (int t = 0; t < 4; t++) {
            int jp = pr_c4[it] * 4 + t;
            int col = (jp < 64) ? jp : (50 + (jp - 64));
            int ok = (pr_row[it] < LL) && ((jp < 64) ? (jp < LL) : ((jp - 64) < LL));
            av[it][t] = ok ? ar[col] : 0.f;
        }
    }

    // ---- Phase B (fused gemm1): [h_in|h_out]^T -> hTsXs; wh picks the 8-nt half ----
    {
        const float* hsrc = hidden + (size_t)b * LL * EMB;
        int mr = wr * 16 + cl;
        const u16* wsrc = wh ? W_out_bf : W_in_bf;
        f32x4 acc1[8];
#pragma unroll
        for (int nt = 0; nt < 8; nt++) acc1[nt] = (f32x4)0.f;
#pragma unroll
        for (int ks = 0; ks < 4; ks++) {
            int k0 = ks * 32;
            bf16x8 a = (mr < LL) ? ld_cvt8(hsrc + mr * 128 + k0 + kg * 8) : (bf16x8)0;
#pragma unroll
            for (int nt = 0; nt < 8; nt++) {
                int wrow = nt * 16 + cl;
                bf16x8 bf = *(const bf16x8*)(wsrc + (size_t)wrow * 128 + k0 + kg * 8);
                acc1[nt] = __builtin_amdgcn_mfma_f32_16x16x32_bf16(a, bf, acc1[nt], 0, 0, 0);
            }
        }
#pragma unroll
        for (int nt = 0; nt < 8; nt++) {
            int col = (wh * 8 + nt) * 16 + cl;
            float bias = (col < 128) ? b_in[col] : b_out[col - 128];
            int r0 = wr * 16 + kg * 4;
            u16x4 p;
#pragma unroll
            for (int j = 0; j < 4; j++)
                p[j] = (r0 + j < LL) ? f2b(acc1[nt][j] + bias) : (u16)0;
            *(u16x4*)&hTsXs[col * 72 + r0] = p;
        }
    }

    // ---- Phase A'' : write prefetched A_io to LDS (loads waited here, not earlier) ----
#pragma unroll
    for (int it = 0; it < 4; it++) {
        u16x4 p;
#pragma unroll
        for (int t = 0; t < 4; t++) p[t] = f2b(av[it][t]);
        *(u16x4*)((char*)AioHs + pr_row[it] * 256 + ((pr_c4[it] * 8) ^ ((pr_row[it] & 7) << 4))) = p;
    }
    __syncthreads();

    // ---- Phase C: einsum inputs = A_io @ [h_in|h_out] (nt half per wh) ----
    f32x4 acc[8];
#pragma unroll
    for (int nt = 0; nt < 8; nt++) acc[nt] = (f32x4)0.f;
#pragma unroll
    for (int ks = 0; ks < 2; ks++) {
#pragma unroll
        for (int nt8 = 0; nt8 < 8; nt8++) {
            int nt = wh * 8 + nt8;
            int k0 = wh * 64 + ks * 32;
            int mr = wr * 16 + cl;
            bf16x8 a = *(const bf16x8*)((const char*)AioHs + mr * 256 +
                        (((k0 << 1) + (kg << 4)) ^ ((mr & 7) << 4)));
            bf16x8 bf = *(const bf16x8*)&hTsXs[(nt * 16 + cl) * 72 + ks * 32 + kg * 8];
            acc[nt8] = __builtin_amdgcn_mfma_f32_16x16x32_bf16(a, bf, acc[nt8], 0, 0, 0);
        }
    }
    __syncthreads();

    // ---- Phase D: inputs -> hTsXs (swizzled), hidden -> AioHs (bf16) ----
#pragma unroll
    for (int nt8 = 0; nt8 < 8; nt8++) {
        int dp = (wh * 8 + nt8) * 16 + cl;
        float bias = (dp < 128) ? b_iah[dp] : b_oah[dp - 128];
#pragma unroll
        for (int j = 0; j < 4; j++) {
            int i = wr * 16 + kg * 4 + j;
            *(u16*)((char*)hTsXs + i * 512 + ((dp * 2) ^ ((i & 7) << 4))) =
                f2b(acc[nt8][j] + bias);
        }
    }
    {
        const float* hsrc = hidden + (size_t)b * LL * EMB;
#pragma unroll
        for (int i2 = 0; i2 < 4; i2++) {
            int lin = i2 * 512 + tid;
            int row = lin >> 5, c4 = lin & 31;
            u16x4 p = (u16x4)0;
            if (row < LL) {
                f32x4 v = *(const f32x4*)(hsrc + row * 128 + c4 * 4);
#pragma unroll
                for (int t = 0; t < 4; t++) p[t] = f2b(v[t]);
            }
            *(u16x4*)((char*)AioHs + row * 256 + ((c4 * 8) ^ ((row & 7) << 4))) = p;
        }
    }
    __syncthreads();

    // ---- Phase E: gi = inputs @ w_ih^T, gh = hidden @ w_hh^T (d = wv*16+cl) ----
    f32x4 acc_ri[4][2];
    f32x4 acc_n1[4];
    f32x4 acc_n2[4];
#pragma unroll
    for (int mt = 0; mt < 4; mt++) {
        acc_ri[mt][0] = (f32x4)0.f; acc_ri[mt][1] = (f32x4)0.f;
        acc_n1[mt] = (f32x4)0.f; acc_n2[mt] = (f32x4)0.f;
    }

#pragma unroll
    for (int ks = 0; ks < 8; ks++) {
        int k0 = ks * 32;
        bf16x8 a[4];
#pragma unroll
        for (int mt = 0; mt < 4; mt++) {
            int mr = mt * 16 + cl;
            a[mt] = *(const bf16x8*)((const char*)hTsXs + mr * 512 +
                     (((k0 << 1) + (kg << 4)) ^ ((mr & 7) << 4)));
        }
#pragma unroll
        for (int g = 0; g < 3; g++) {
            int brow = g * 128 + wv * 16 + cl;
            bf16x8 bw = *(const bf16x8*)(w_ih_bf + (size_t)brow * 256 + k0 + kg * 8);
#pragma unroll
            for (int mt = 0; mt < 4; mt++) {
                f32x4* dst = (g < 2) ? &acc_ri[mt][g] : &acc_n1[mt];
                *dst = __builtin_amdgcn_mfma_f32_16x16x32_bf16(a[mt], bw, *dst, 0, 0, 0);
            }
        }
    }
#pragma unroll
    for (int ks = 0; ks < 4; ks++) {
        int k0 = ks * 32;
        bf16x8 a[4];
#pragma unroll
        for (int mt = 0; mt < 4; mt++) {
            int mr = mt * 16 + cl;
            a[mt] = *(const bf16x8*)((const char*)AioHs + mr * 256 +
                     (((k0 << 1) + (kg << 4)) ^ ((mr & 7) << 4)));
        }
#pragma unroll
        for (int g = 0; g < 3; g++) {
            int brow = g * 128 + wv * 16 + cl;
            bf16x8 bw = *(const bf16x8*)(w_hh_bf + (size_t)brow * 128 + k0 + kg * 8);
#pragma unroll
            for (int mt = 0; mt < 4; mt++) {
                f32x4* dst = (g < 2) ? &acc_ri[mt][g] : &acc_n2[mt];
                *dst = __builtin_amdgcn_mfma_f32_16x16x32_bf16(a[mt], bw, *dst, 0, 0, 0);
            }
        }
    }

    // ---- Phase F: GRU gates ----
    {
        int d = wv * 16 + cl;
        float br = b_ih[d] + b_hh[d];
        float bi = b_ih[128 + d] + b_hh[128 + d];
        float bn1 = b_ih[256 + d], bn2 = b_hh[256 + d];
#pragma unroll
        for (int mt = 0; mt < 4; mt++)
#pragma unroll
            for (int j = 0; j < 4; j++) {
                int row = mt * 16 + kg * 4 + j;
                if (row >= LL) continue;
                float rg = sigmoidf_(acc_ri[mt][0][j] + br);
                float ig = sigmoidf_(acc_ri[mt][1][j] + bi);
                float ng = tanhf(acc_n1[mt][j] + bn1 + rg * (acc_n2[mt][j] + bn2));
                u16 hb = *(const u16*)((const char*)AioHs + row * 256 + ((d * 2) ^ ((row & 7) << 4)));
                float h = u2f(hb);
                hy[((size_t)b * LL + row) * 128 + d] = ng + ig * (h - ng);
            }
    }
}

extern "C" void kernel_launch(void* const* d_in, const int* in_sizes, int n_in,
                              void* d_out, int out_size, void* d_ws, size_t ws_size,
                              hipStream_t stream) {
    (void)n_in; (void)out_size; (void)ws_size;
    const int*   adj_row      = (const int*)d_in[0];
    const int*   adj_col      = (const int*)d_in[1];
    const float* adj_val      = (const float*)d_in[2];
    const float* embedding    = (const float*)d_in[3];
    const int*   session_item = (const int*)d_in[4];
    const float* session_len  = (const float*)d_in[5];
    const float* Dm           = (const float*)d_in[6];
    const float* A_sess       = (const float*)d_in[7];
    const float* A_gnn        = (const float*)d_in[8];
    const int*   alias_pos    = (const int*)d_in[9];
    const float* hidden       = (const float*)d_in[10];
    const float* W_in         = (const float*)d_in[11];
    const float* b_in         = (const float*)d_in[12];
    const float* W_out        = (const float*)d_in[13];
    const float* b_out        = (const float*)d_in[14];
    const float* w_ih         = (const float*)d_in[15];
    const float* b_ih         = (const float*)d_in[16];
    const float* w_hh         = (const float*)d_in[17];
    const float* b_hh         = (const float*)d_in[18];
    const float* b_iah        = (const float*)d_in[19];
    const float* b_oah        = (const float*)d_in[20];
    const int E = in_sizes[0];

    float* out0 = (float*)d_out;
    float* out1 = out0 + 6400000;
    float* out2 = out1 + 131072;

    float* ws = (float*)d_ws;
    u16*  emb_bf  = (u16*)ws;                    // [0, 3.2M) live through gathers
    int*  bcnt  = (int*)(ws + 3200000);          // scratch under accA region
    int*  sofs  = (int*)(ws + 3230000);
    int*  btot  = (int*)(ws + 3260000);
    u16*  accA_bf = (u16*)(ws + 3200000);        // [3.2M, 6.4M) gather<0> out
    u32*  eg    = (u32*)(ws + 6400000);          // [6.4M, 8.0M)
    u64*  egs   = (u64*)(ws + 8000000);          // [8.0M, 11.2M)
    float* sess  = ws + 11200000;
    u16*   sessT = (u16*)(ws + 11350000);
    u16*   t1T   = (u16*)(ws + 11400000);
    u16*   s1T   = (u16*)(ws + 11450000);
    u16*   t2T   = (u16*)(ws + 11500000);
    float* s1    = ws + 11550000;
    float* s2    = ws + 11700000;
    u16*   A_bf  = (u16*)(ws + 11850000);
    u16*   D_bf  = (u16*)(ws + 12400000);
    int*   row_ptr = (int*)(ws + 12950000);
    int*   bofs    = row_ptr + NN + 1;
    u16* w_ih_bf   = (u16*)(ws + 13107200);
    u16* w_hh_bf   = w_ih_bf + 98304;
    u16* W_in_bf   = w_hh_bf + 49152;
    u16* W_out_bf  = W_in_bf + 16384;

    int chunk = (E + NEB - 1) / NEB;

    // ---- prep: converts + chunked bucket counts (no global atomics) ----
    prep_kernel<<<2048, 256, 0, stream>>>(embedding, A_sess, Dm, w_ih, w_hh, W_in, W_out,
                                          emb_bf, A_bf, D_bf, w_ih_bf, w_hh_bf, W_in_bf, W_out_bf,
                                          adj_row, bcnt, E, chunk);

    // ---- Part 1: bucket sort + 2 bf16 gather layers ----
    bktscan_kernel<<<NBK, 512, 0, stream>>>(bcnt, sofs, btot);
    btotal_kernel<<<1, 64, 0, stream>>>(btot, bofs, E);
    emit_kernel<<<NEB, 256, 0, stream>>>(adj_row, adj_col, adj_val, sofs, bofs, egs, E, chunk);
    binsort2_kernel<<<NBK, 1024, 0, stream>>>(egs, bofs, row_ptr, eg, E);
    gatherb_kernel<0><<<(NN + 3) / 4, 256, 0, stream>>>(row_ptr, eg, emb_bf, embedding, accA_bf, (float*)nullptr);
    gatherb_kernel<1><<<(NN + 3) / 4, 256, 0, stream>>>(row_ptr, eg, accA_bf, embedding, (u16*)nullptr, out0);

    // ---- Part 2: LineConv (MFMA chain, re-associated s_next = D @ (A @ s)) ----
    sess_pool_kernel<<<BB, 128, 0, stream>>>(session_item, embedding, session_len, sess, sessT);
    mm_mfma_kernel<1, 0><<<64, 256, 0, stream>>>(A_bf, sessT, t1T, (float*)nullptr);
    mm_mfma_kernel<1, 1><<<64, 256, 0, stream>>>(D_bf, t1T, s1T, s1);
    mm_mfma_kernel<1, 0><<<64, 256, 0, stream>>>(A_bf, s1T, t2T, (float*)nullptr);
    mm_mfma_kernel<0, 1><<<64, 256, 0, stream>>>(D_bf, t2T, (u16*)nullptr, s2);
    out1_kernel<<<(131072 + 255) / 256, 256, 0, stream>>>(sess, s1, s2, out1, 131072);

    // ---- Part 3: GNN fully fused, 8-wave blocks, one dispatch over all 1024 sessions ----
    gnn_tail_kernel<<<BB, 512, 0, stream>>>(hidden, W_in_bf, W_out_bf, b_in, b_out,
                                            A_gnn, alias_pos, b_iah, b_oah,
                                            w_ih_bf, b_ih, w_hh_bf, b_hh, out2);
}